// Round 1
// baseline (523.539 us; speedup 1.0000x reference)
//
#include <hip/hip_runtime.h>

// ExodusNet: per-timestep dense (32->1) + ExpLeak scan + LIF (SingleSpike,
// MembraneSubtract, norm_input=True). B=32768, F=32, T=100.
// Kernel roofline: 419 MB read + 13 MB write -> ~69 us at 6.3 TB/s.
// Bench dur_us also contains harness restore/poison (~390 us fixed).
//
// PRECISION CONTRACT (round 1 post-mortem — DO NOT CHANGE THE ARITHMETIC):
// output is binary spikes; a near-threshold flip costs absmax=1.0. ref=np is
// fp32. Bit-exact parity requires: dot sequential f=0..31 in fp32 with
// separate mul/add rounding (contract off); scans fp32 mul-then-add no-fma;
// ALPHA=(float)exp(-0.1), OMA=(float)(1.0-exp(-0.1)). Rounds 2-4: absmax=0.0.
//
// Round 5 change (phase-decoupling hypothesis): rounds 2/3 (strided loads)
// and round 4 (perfect LDS-staged loads) measured IDENTICAL dur -> the load
// pattern is not the limiter. What every variant shares: the fused per-block
// scan tail — a ~1600-2000 cyc dependent fp32 chain on 4/128 lanes, run
// 8192 times at 6 waves/CU, convoyed behind two barriers. Split instead:
//   K1 snn_dense: stage slab -> LDS -> exact dense -> currents to d_ws.
//     Compute/block (~900 cyc) << memory/block (~5100 cyc) -> 3 resident
//     blocks/CU keep the HBM pipe full; should run at fill-kernel BW (~81%).
//   K2 snn_scan: one thread per batch row (32768-way parallel), exact fused
//     ExpLeak+LIF scan; 26 MB round-trip ~ 5-8 us.
// Currents pass through global fp32 -> bit-identical to the LDS fp32 path.

typedef float vf4 __attribute__((ext_vector_type(4)));

constexpr int T_STEPS = 100;
constexpr int F_IN    = 32;
constexpr int NB      = 4;                    // batch rows per block (K1)
constexpr int BLOCK   = 128;
constexpr int QT      = T_STEPS / 4;          // 25 float4 per time row
constexpr int ROWF    = T_STEPS + 4;          // 104: padded currents row (fallback)
constexpr int SLABF   = NB * F_IN * T_STEPS;  // 12800 floats = 51200 B
constexpr int CHUNKS  = SLABF / (4 * BLOCK);  // 25 float4 loads per thread

// ---------------- K1: streaming dense only ----------------
__global__ __launch_bounds__(BLOCK) void snn_dense(
    const float* __restrict__ x,   // (B, 32, 100)
    const float* __restrict__ w,   // (1, 32)
    float* __restrict__ cur_g)     // (B, 100) workspace
{
#pragma clang fp contract(off)
    __shared__ float xs[SLABF];        // 51.2 KB: verbatim x slab (bit-exact)

    const int tid = threadIdx.x;
    const long long blk = blockIdx.x;
    const float* slab = x + blk * (long long)SLABF;

    // Phase A: stage slab -> LDS, perfectly lane-linear 1-KB float4 loads
    // (m13 pattern). x is read exactly once chip-wide -> nontemporal.
    vf4 v[CHUNKS];
#pragma unroll
    for (int c = 0; c < CHUNKS; ++c)
        v[c] = __builtin_nontemporal_load((const vf4*)slab + c * BLOCK + tid);
#pragma unroll
    for (int c = 0; c < CHUNKS; ++c)
        ((vf4*)xs)[c * BLOCK + tid] = v[c];

    float wf[F_IN];
#pragma unroll
    for (int f = 0; f < F_IN; ++f) wf[f] = w[f];

    __syncthreads();

    // Phase B: cur[nb][t] = sum_f xs[nb, f, t] * w[f]
    // fp32, sequential over f, separate mul/add rounding (no fma).
    if (tid < NB * QT) {
        const int nb = tid / QT;
        const int j  = tid - nb * QT;
        const float* xr = xs + nb * (F_IN * T_STEPS) + 4 * j;
        float a0 = 0.0f, a1 = 0.0f, a2 = 0.0f, a3 = 0.0f;
#pragma unroll
        for (int f = 0; f < F_IN; ++f) {
            const vf4 xv = *(const vf4*)(xr + f * T_STEPS);  // ds_read_b128
            a0 = a0 + xv.x * wf[f];
            a1 = a1 + xv.y * wf[f];
            a2 = a2 + xv.z * wf[f];
            a3 = a3 + xv.w * wf[f];
        }
        // Coalesced: block writes 4 contiguous 400-B rows (1600 B).
        vf4* dst = (vf4*)(cur_g + (blk * NB + nb) * (long long)T_STEPS + 4 * j);
        *dst = vf4{a0, a1, a2, a3};
    }
}

// ---------------- K2: fully parallel scan, 1 thread / batch row ----------------
__global__ __launch_bounds__(BLOCK) void snn_scan(
    const float* __restrict__ cur_g,  // (B, 100)
    float* __restrict__ out)          // (B, 1, 100)
{
#pragma clang fp contract(off)
    const long long b = (long long)blockIdx.x * BLOCK + threadIdx.x;
    const vf4* row = (const vf4*)(cur_g + b * (long long)T_STEPS);

    // 25 independent float4 loads, hoisted for MLP. Per-lane 400-B stride:
    // each 64-B line is consumed 4x by the same lane -> L1 amortizes
    // (51.2 KB working set per block), total fetch = 13 MB once.
    vf4 rv[QT];
#pragma unroll
    for (int q = 0; q < QT; ++q) rv[q] = row[q];

    const double ALPHA64 = 0.90483741803595957316;  // exp(-1/10) in f64
    const float  A   = (float)ALPHA64;
    const float  OMA = (float)(1.0 - ALPHA64);      // f64 sub -> f32 cast
    float syn = 0.0f, vmem = 0.0f;
    vf4* op = (vf4*)(out + b * (long long)T_STEPS);
#pragma unroll
    for (int q = 0; q < QT; ++q) {
        vf4 s4;
#pragma unroll
        for (int k = 0; k < 4; ++k) {               // static indices only
            syn  = (A * syn) + rv[q][k];
            vmem = (A * vmem) + (OMA * syn);
            const float s = (vmem >= 1.0f) ? 1.0f : 0.0f;
            vmem = vmem - s;
            s4[k] = s;
        }
        op[q] = s4;
    }
}

// ---------------- Fallback: round-4 fused kernel (if ws too small) ----------------
__global__ __launch_bounds__(BLOCK) void snn_fused(
    const float* __restrict__ x, const float* __restrict__ w,
    float* __restrict__ out)
{
#pragma clang fp contract(off)
    __shared__ float xs[SLABF];
    __shared__ float cur[NB * ROWF];

    const int tid = threadIdx.x;
    const long long blk = blockIdx.x;
    const float* slab = x + blk * (long long)SLABF;

    vf4 v[CHUNKS];
#pragma unroll
    for (int c = 0; c < CHUNKS; ++c)
        v[c] = __builtin_nontemporal_load((const vf4*)slab + c * BLOCK + tid);
#pragma unroll
    for (int c = 0; c < CHUNKS; ++c)
        ((vf4*)xs)[c * BLOCK + tid] = v[c];

    float wf[F_IN];
#pragma unroll
    for (int f = 0; f < F_IN; ++f) wf[f] = w[f];

    __syncthreads();

    if (tid < NB * QT) {
        const int nb = tid / QT;
        const int j  = tid - nb * QT;
        const float* xr = xs + nb * (F_IN * T_STEPS) + 4 * j;
        float a0 = 0.0f, a1 = 0.0f, a2 = 0.0f, a3 = 0.0f;
#pragma unroll
        for (int f = 0; f < F_IN; ++f) {
            const vf4 xv = *(const vf4*)(xr + f * T_STEPS);
            a0 = a0 + xv.x * wf[f];
            a1 = a1 + xv.y * wf[f];
            a2 = a2 + xv.z * wf[f];
            a3 = a3 + xv.w * wf[f];
        }
        vf4* dst = (vf4*)(cur + nb * ROWF + 4 * j);
        *dst = vf4{a0, a1, a2, a3};
    }
    __syncthreads();

    if (tid < NB) {
        const double ALPHA64 = 0.90483741803595957316;
        const float  A   = (float)ALPHA64;
        const float  OMA = (float)(1.0 - ALPHA64);
        float syn = 0.0f, vmem = 0.0f;
        const float* row = cur + tid * ROWF;
        vf4* op = (vf4*)(out + (blk * NB + tid) * (long long)T_STEPS);
#pragma unroll
        for (int q = 0; q < QT; ++q) {
            vf4 s4;
#pragma unroll
            for (int k = 0; k < 4; ++k) {
                syn  = (A * syn) + row[4 * q + k];
                vmem = (A * vmem) + (OMA * syn);
                const float s = (vmem >= 1.0f) ? 1.0f : 0.0f;
                vmem = vmem - s;
                s4[k] = s;
            }
            op[q] = s4;
        }
    }
}

extern "C" void kernel_launch(void* const* d_in, const int* in_sizes, int n_in,
                              void* d_out, int out_size, void* d_ws, size_t ws_size,
                              hipStream_t stream) {
    const float* x  = (const float*)d_in[0];
    const float* w  = (const float*)d_in[1];
    float* out      = (float*)d_out;
    const int B       = in_sizes[0] / (F_IN * T_STEPS);  // 32768
    const int nblocks = B / NB;                          // 8192

    const size_t cur_bytes = (size_t)B * T_STEPS * sizeof(float);  // 13.1 MB
    if (ws_size >= cur_bytes && d_ws != nullptr) {
        float* cur_g = (float*)d_ws;
        snn_dense<<<nblocks, BLOCK, 0, stream>>>(x, w, cur_g);
        snn_scan<<<B / BLOCK, BLOCK, 0, stream>>>(cur_g, out);  // 256 blocks
    } else {
        snn_fused<<<nblocks, BLOCK, 0, stream>>>(x, w, out);
    }
}